// Round 3
// baseline (528.234 us; speedup 1.0000x reference)
//
#include <hip/hip_runtime.h>
#include <math.h>

// Problem constants
#define B_   64
#define S_   64
#define W_   12
#define V_   32000
#define SYM_ 128
#define HID_ 256
#define E_   64
#define R_   32

// ---------------------------------------------------------------------------
// K1: sentence / query embedding sums
// ---------------------------------------------------------------------------
__global__ __launch_bounds__(128) void k_embed(
    const int* __restrict__ story, const int* __restrict__ query,
    const float* __restrict__ we, const float* __restrict__ pe,
    float* __restrict__ sent, float* __restrict__ qsum) {
  int blk = blockIdx.x;
  int e = threadIdx.x;
  if (blk < B_ * S_) {
    const int* idx = story + blk * W_;
    float acc = 0.f;
#pragma unroll
    for (int w = 0; w < W_; ++w)
      acc = fmaf(we[(long)idx[w] * SYM_ + e], pe[w * SYM_ + e], acc);
    sent[blk * SYM_ + e] = acc;
  } else {
    int b = blk - B_ * S_;
    const int* idx = query + b * W_;
    float acc = 0.f;
#pragma unroll
    for (int w = 0; w < W_; ++w)
      acc = fmaf(we[(long)idx[w] * SYM_ + e], pe[w * SYM_ + e], acc);
    qsum[b * SYM_ + e] = acc;
  }
}

// ---------------------------------------------------------------------------
// K2: two-layer MLP heads (unchanged)
// ---------------------------------------------------------------------------
__global__ __launch_bounds__(256) void k_mlp(
    const float* __restrict__ X,
    const float* __restrict__ eW1, const float* __restrict__ eb1,
    const float* __restrict__ eW2, const float* __restrict__ eb2,
    const float* __restrict__ rW1, const float* __restrict__ rb1,
    const float* __restrict__ rW2, const float* __restrict__ rb2,
    float* __restrict__ oE0, float* __restrict__ oE1,
    float* __restrict__ oR0, float* __restrict__ oR1, float* __restrict__ oR2) {
  __shared__ float XT[128 * 68];
  __shared__ float HT[64 * 68];

  int h = blockIdx.x % 5;
  int tile = blockIdx.x / 5;
  int rowbase = tile * 64;
  bool isE = (h < 2);
  const float* W1 = isE ? eW1 + h * (SYM_ * HID_) : rW1 + (h - 2) * (SYM_ * HID_);
  const float* b1 = isE ? eb1 + h * HID_ : rb1 + (h - 2) * HID_;
  const float* W2 = isE ? eW2 + h * (HID_ * E_) : rW2 + (h - 2) * (HID_ * R_);
  const float* b2 = isE ? eb2 + h * E_ : rb2 + (h - 2) * R_;
  float* out = (h == 0) ? oE0 : (h == 1) ? oE1 : (h == 2) ? oR0 : (h == 3) ? oR1 : oR2;

  int tid = threadIdx.x;
  for (int i = tid; i < 64 * 128; i += 256) {
    int row = i >> 7, k = i & 127;
    XT[k * 68 + row] = X[(long)(rowbase + row) * SYM_ + k];
  }
  __syncthreads();

  int tr = tid >> 4, tc = tid & 15;
  float accE[4][4] = {};
  float accR[4][2] = {};

  for (int p = 0; p < 4; ++p) {
    int cbase = p * 64;
    float4 b1v = *(const float4*)(b1 + cbase + 4 * tc);
    float a[4][4] = {};
#pragma unroll 4
    for (int k = 0; k < 128; ++k) {
      float4 xa = *(const float4*)&XT[k * 68 + 4 * tr];
      float4 wb = *(const float4*)(W1 + k * HID_ + cbase + 4 * tc);
      float xs[4] = {xa.x, xa.y, xa.z, xa.w};
      float wsv[4] = {wb.x, wb.y, wb.z, wb.w};
#pragma unroll
      for (int i = 0; i < 4; ++i)
#pragma unroll
        for (int j = 0; j < 4; ++j) a[i][j] = fmaf(xs[i], wsv[j], a[i][j]);
    }
    __syncthreads();
    float b1s[4] = {b1v.x, b1v.y, b1v.z, b1v.w};
#pragma unroll
    for (int i = 0; i < 4; ++i)
#pragma unroll
      for (int j = 0; j < 4; ++j)
        HT[(4 * tc + j) * 68 + 4 * tr + i] = tanhf(a[i][j] + b1s[j]);
    __syncthreads();
    if (isE) {
#pragma unroll 2
      for (int c = 0; c < 64; ++c) {
        float4 h4 = *(const float4*)&HT[c * 68 + 4 * tr];
        float4 w4 = *(const float4*)(W2 + (long)(cbase + c) * E_ + 4 * tc);
        float hs[4] = {h4.x, h4.y, h4.z, h4.w};
        float wv[4] = {w4.x, w4.y, w4.z, w4.w};
#pragma unroll
        for (int i = 0; i < 4; ++i)
#pragma unroll
          for (int j = 0; j < 4; ++j) accE[i][j] = fmaf(hs[i], wv[j], accE[i][j]);
      }
    } else {
#pragma unroll 2
      for (int c = 0; c < 64; ++c) {
        float4 h4 = *(const float4*)&HT[c * 68 + 4 * tr];
        float2 w2 = *(const float2*)(W2 + (long)(cbase + c) * R_ + 2 * tc);
        float hs[4] = {h4.x, h4.y, h4.z, h4.w};
#pragma unroll
        for (int i = 0; i < 4; ++i) {
          accR[i][0] = fmaf(hs[i], w2.x, accR[i][0]);
          accR[i][1] = fmaf(hs[i], w2.y, accR[i][1]);
        }
      }
    }
  }
  if (isE) {
    float4 b2v = *(const float4*)(b2 + 4 * tc);
#pragma unroll
    for (int i = 0; i < 4; ++i) {
      float4 o4 = make_float4(accE[i][0] + b2v.x, accE[i][1] + b2v.y,
                              accE[i][2] + b2v.z, accE[i][3] + b2v.w);
      *(float4*)(out + (long)(rowbase + 4 * tr + i) * E_ + 4 * tc) = o4;
    }
  } else {
    float2 b2v = *(const float2*)(b2 + 2 * tc);
#pragma unroll
    for (int i = 0; i < 4; ++i) {
      float2 o2 = make_float2(accR[i][0] + b2v.x, accR[i][1] + b2v.y);
      *(float2*)(out + (long)(rowbase + 4 * tr + i) * R_ + 2 * tc) = o2;
    }
  }
}

// ---------------------------------------------------------------------------
// K_gram: per (b, m) compute coefficient matrix
//   W[b,m,s,j] = (sE_s . jE_j) * (sR_s . jR_j)
// m: 0 Wa=(G11,P11) 1 Wc=(G11,P12) 2 Wd=(G12,P13)
//    3 Ma=(G11,P21) 4 Mc=(G11,P22) 5 Md=(G12,P23)
//    6 Ba=(G21,P31) 7 Bc=(G21,P32) 8 Bd=(G22,P33)
//  Gxy[s,j] = ex_s . ey_j ; Pkl[s,j] = rk_s . rl_j
// ---------------------------------------------------------------------------
__global__ __launch_bounds__(256) void k_gram(
    const float* __restrict__ e1, const float* __restrict__ e2,
    const float* __restrict__ r1, const float* __restrict__ r2,
    const float* __restrict__ r3, float* __restrict__ Wc) {
  int b = blockIdx.x / 9, m = blockIdx.x % 9;
  const float* sE = ((m < 6) ? e1 : e2) + (long)b * S_ * E_;
  const float* jE = ((m == 2 || m == 5 || m == 8) ? e2 : e1) + (long)b * S_ * E_;
  int sk = m / 3, jk = m % 3;
  const float* sR = ((sk == 0) ? r1 : (sk == 1) ? r2 : r3) + (long)b * S_ * R_;
  const float* jR = ((jk == 0) ? r1 : (jk == 1) ? r2 : r3) + (long)b * S_ * R_;

  __shared__ float Es[64][68], Ej[64][68], Rs[64][36], Rj[64][36];
  int tid = threadIdx.x;
  for (int i = tid; i < 1024; i += 256) {
    int row = i >> 4, c = i & 15;
    *(float4*)&Es[row][4 * c] = *(const float4*)(sE + row * 64 + 4 * c);
    *(float4*)&Ej[row][4 * c] = *(const float4*)(jE + row * 64 + 4 * c);
  }
  for (int i = tid; i < 512; i += 256) {
    int row = i >> 3, c = i & 7;
    *(float4*)&Rs[row][4 * c] = *(const float4*)(sR + row * 32 + 4 * c);
    *(float4*)&Rj[row][4 * c] = *(const float4*)(jR + row * 32 + 4 * c);
  }
  __syncthreads();

  int s0 = (tid >> 4) * 4, j0 = (tid & 15) * 4;
  float ed[4][4] = {}, rd[4][4] = {};
#pragma unroll 4
  for (int k = 0; k < 16; ++k) {
    float4 es[4], ej[4];
#pragma unroll
    for (int i = 0; i < 4; ++i) {
      es[i] = *(const float4*)&Es[s0 + i][4 * k];
      ej[i] = *(const float4*)&Ej[j0 + i][4 * k];
    }
#pragma unroll
    for (int i = 0; i < 4; ++i)
#pragma unroll
      for (int j = 0; j < 4; ++j)
        ed[i][j] = fmaf(es[i].x, ej[j].x, fmaf(es[i].y, ej[j].y,
                   fmaf(es[i].z, ej[j].z, fmaf(es[i].w, ej[j].w, ed[i][j]))));
  }
#pragma unroll 4
  for (int k = 0; k < 8; ++k) {
    float4 rs[4], rj[4];
#pragma unroll
    for (int i = 0; i < 4; ++i) {
      rs[i] = *(const float4*)&Rs[s0 + i][4 * k];
      rj[i] = *(const float4*)&Rj[j0 + i][4 * k];
    }
#pragma unroll
    for (int i = 0; i < 4; ++i)
#pragma unroll
      for (int j = 0; j < 4; ++j)
        rd[i][j] = fmaf(rs[i].x, rj[j].x, fmaf(rs[i].y, rj[j].y,
                   fmaf(rs[i].z, rj[j].z, fmaf(rs[i].w, rj[j].w, rd[i][j]))));
  }
  float* wout = Wc + (((long)(b * 9 + m) * 64) * 64);
#pragma unroll
  for (int i = 0; i < 4; ++i) {
    float4 o4 = make_float4(ed[i][0] * rd[i][0], ed[i][1] * rd[i][1],
                            ed[i][2] * rd[i][2], ed[i][3] * rd[i][3]);
    *(float4*)(wout + (s0 + i) * 64 + j0) = o4;
  }
}

// ---------------------------------------------------------------------------
// K_scan (factored): one wave per b, lane = f. Triangular scalar recurrence:
//   wh_s = sum_{j<s} Wa[s,j]a_j + Wc[s,j]c_j + Wd[s,j]d_j   (same for mh, bh)
//   a_s = e2[s,f]-wh ; c_s = wh-mh ; d_s = e1[s,f]-bh
// History (a,c,d) per (j,f) in LDS float4; coefficients via SGPR loads.
// ---------------------------------------------------------------------------
__global__ __launch_bounds__(64) void k_scan(
    const float* __restrict__ e1, const float* __restrict__ e2,
    const float* __restrict__ Wc, float4* __restrict__ acd) {
  __shared__ float4 hist[64 * 64];  // [j][f]
  int b = blockIdx.x;
  int f = threadIdx.x;
  const float* Wb = Wc + (long)b * 9 * 4096;

  for (int s = 0; s < 64; ++s) {
    // prefetch step inputs (independent of the dot loop)
    float e1sf = e1[((long)b * 64 + s) * 64 + f];
    float e2sf = e2[((long)b * 64 + s) * 64 + f];
    const float* w0 = Wb + 0 * 4096 + s * 64;
    const float* w1 = Wb + 1 * 4096 + s * 64;
    const float* w2 = Wb + 2 * 4096 + s * 64;
    const float* w3 = Wb + 3 * 4096 + s * 64;
    const float* w4 = Wb + 4 * 4096 + s * 64;
    const float* w5 = Wb + 5 * 4096 + s * 64;
    const float* w6 = Wb + 6 * 4096 + s * 64;
    const float* w7 = Wb + 7 * 4096 + s * 64;
    const float* w8 = Wb + 8 * 4096 + s * 64;
    float aw = 0.f, cw = 0.f, dw = 0.f;
    float am = 0.f, cm = 0.f, dm = 0.f;
    float ab = 0.f, cb = 0.f, db = 0.f;
#pragma unroll 2
    for (int j = 0; j < s; ++j) {
      float4 h = hist[j * 64 + f];
      aw = fmaf(w0[j], h.x, aw);
      cw = fmaf(w1[j], h.y, cw);
      dw = fmaf(w2[j], h.z, dw);
      am = fmaf(w3[j], h.x, am);
      cm = fmaf(w4[j], h.y, cm);
      dm = fmaf(w5[j], h.z, dm);
      ab = fmaf(w6[j], h.x, ab);
      cb = fmaf(w7[j], h.y, cb);
      db = fmaf(w8[j], h.z, db);
    }
    float wh = (aw + cw) + dw;
    float mh = (am + cm) + dm;
    float bh = (ab + cb) + db;
    float a = e2sf - wh;
    float c = wh - mh;
    float d = e1sf - bh;
    float4 h4 = make_float4(a, c, d, 0.f);
    hist[s * 64 + f] = h4;
    acd[((long)b * 64 + s) * 64 + f] = h4;
  }
}

// ---------------------------------------------------------------------------
// K_infer (factored): per b, i1->i2->i3 without TPR:
//   y_p[f] = sum_j (u1_j*vr1_j)a[j,f] + (u1_j*vr2_j)c[j,f] + (u2_j*vr3_j)d[j,f]
//   u1_j = i_prev . e1_j, u2_j = i_prev . e2_j, vrk_j = qr_p . rk_j
// ---------------------------------------------------------------------------
__global__ __launch_bounds__(256) void k_infer(
    const float4* __restrict__ acd,
    const float* __restrict__ e1, const float* __restrict__ e2,
    const float* __restrict__ r1, const float* __restrict__ r2,
    const float* __restrict__ r3,
    const float* __restrict__ qe1, const float* __restrict__ qr1,
    const float* __restrict__ qr2, const float* __restrict__ qr3,
    const float* __restrict__ lng, const float* __restrict__ lnb,
    float* __restrict__ isum) {
  int b = blockIdx.x, tid = threadIdx.x;
  __shared__ float4 hist[64 * 64];  // [j][f]
  __shared__ float vlds[9 * 64];    // [p*3+k][j]
  __shared__ float ivec[64];
  __shared__ float u1s[64], u2s[64];
  __shared__ float dsc[64];

  for (int i = tid; i < 4096; i += 256) hist[i] = acd[(long)b * 4096 + i];
  for (int idx = tid; idx < 576; idx += 256) {
    int pk = idx >> 6, j = idx & 63;
    int p = pk / 3, k = pk % 3;
    const float* rv = ((k == 0) ? r1 : (k == 1) ? r2 : r3) + ((long)b * 64 + j) * 32;
    const float* q = ((p == 0) ? qr1 : (p == 1) ? qr2 : qr3) + b * 32;
    float acc = 0.f;
#pragma unroll
    for (int t = 0; t < 8; ++t) {
      float4 rv4 = *(const float4*)(rv + 4 * t);
      float4 q4 = *(const float4*)(q + 4 * t);
      acc = fmaf(rv4.x, q4.x, fmaf(rv4.y, q4.y,
            fmaf(rv4.z, q4.z, fmaf(rv4.w, q4.w, acc))));
    }
    vlds[pk * 64 + j] = acc;
  }
  if (tid < 64) ivec[tid] = qe1[b * 64 + tid];
  __syncthreads();

  float isacc = 0.f;
  int f = tid >> 2, q = tid & 3;
  for (int p = 0; p < 3; ++p) {
    // u-dots: i_prev . e1_j / e2_j
    if (tid < 128) {
      int which = tid >> 6, j = tid & 63;
      const float* erow = (which ? e2 : e1) + ((long)b * 64 + j) * 64;
      const float4* iv4 = (const float4*)ivec;
      float acc = 0.f;
#pragma unroll
      for (int t = 0; t < 16; ++t) {
        float4 ev = *(const float4*)(erow + 4 * t);
        float4 c4 = iv4[t];
        acc = fmaf(ev.x, c4.x, fmaf(ev.y, c4.y,
              fmaf(ev.z, c4.z, fmaf(ev.w, c4.w, acc))));
      }
      if (which) u2s[j] = acc; else u1s[j] = acc;
    }
    __syncthreads();
    // y[f] over j
    float part = 0.f;
#pragma unroll 4
    for (int jj = 0; jj < 16; ++jj) {
      int j = q * 16 + jj;
      float4 h = hist[j * 64 + f];
      float ca = u1s[j] * vlds[(p * 3 + 0) * 64 + j];
      float cc = u1s[j] * vlds[(p * 3 + 1) * 64 + j];
      float cd = u2s[j] * vlds[(p * 3 + 2) * 64 + j];
      part = fmaf(ca, h.x, fmaf(cc, h.y, fmaf(cd, h.z, part)));
    }
    part += __shfl_xor(part, 1, 64);
    part += __shfl_xor(part, 2, 64);
    if (q == 0) dsc[f] = part;
    __syncthreads();
    if (tid < 64) {
      float v = dsc[tid];
      float mu = v;
#pragma unroll
      for (int mm = 1; mm <= 32; mm <<= 1) mu += __shfl_xor(mu, mm, 64);
      mu *= (1.f / 64.f);
      float d = v - mu;
      float vr = d * d;
#pragma unroll
      for (int mm = 1; mm <= 32; mm <<= 1) vr += __shfl_xor(vr, mm, 64);
      vr *= (1.f / 64.f);
      float iv = d * (1.f / sqrtf(vr + 1e-5f)) * lng[p * 64 + tid] + lnb[p * 64 + tid];
      ivec[tid] = iv;
      isacc += iv;
    }
    __syncthreads();
  }
  if (tid < 64) isum[b * 64 + tid] = isacc;
}

// ---------------------------------------------------------------------------
// K5: out[b,v] = sum_e isum[b,e] * Z[e,v]
// ---------------------------------------------------------------------------
__global__ __launch_bounds__(256) void k_final(
    const float* __restrict__ isum, const float* __restrict__ Zm,
    float* __restrict__ out) {
  __shared__ float isT[64 * 68];
  int tid = threadIdx.x;
  for (int i = tid; i < 4096; i += 256) {
    int bb = i >> 6, e = i & 63;
    isT[e * 68 + bb] = isum[i];
  }
  __syncthreads();
  int tr = tid >> 4, tc = tid & 15;
  int v0 = blockIdx.x * 64 + tc * 4;
  float acc[4][4] = {};
#pragma unroll 2
  for (int e = 0; e < 64; ++e) {
    float4 a4 = *(const float4*)&isT[e * 68 + 4 * tr];
    float4 z4 = *(const float4*)(Zm + (long)e * V_ + v0);
    float as[4] = {a4.x, a4.y, a4.z, a4.w};
    float zs[4] = {z4.x, z4.y, z4.z, z4.w};
#pragma unroll
    for (int i = 0; i < 4; ++i)
#pragma unroll
      for (int j = 0; j < 4; ++j) acc[i][j] = fmaf(as[i], zs[j], acc[i][j]);
  }
#pragma unroll
  for (int i = 0; i < 4; ++i) {
    float4 o4 = make_float4(acc[i][0], acc[i][1], acc[i][2], acc[i][3]);
    *(float4*)(out + (long)(4 * tr + i) * V_ + v0) = o4;
  }
}

// ---------------------------------------------------------------------------
extern "C" void kernel_launch(void* const* d_in, const int* in_sizes, int n_in,
                              void* d_out, int out_size, void* d_ws, size_t ws_size,
                              hipStream_t stream) {
  const int* story = (const int*)d_in[0];
  const int* query = (const int*)d_in[1];
  const float* we = (const float*)d_in[2];
  const float* pe = (const float*)d_in[3];
  const float* ueW1 = (const float*)d_in[4];
  const float* ueb1 = (const float*)d_in[5];
  const float* ueW2 = (const float*)d_in[6];
  const float* ueb2 = (const float*)d_in[7];
  const float* urW1 = (const float*)d_in[8];
  const float* urb1 = (const float*)d_in[9];
  const float* urW2 = (const float*)d_in[10];
  const float* urb2 = (const float*)d_in[11];
  const float* ieW1 = (const float*)d_in[12];
  const float* ieb1 = (const float*)d_in[13];
  const float* ieW2 = (const float*)d_in[14];
  const float* ieb2 = (const float*)d_in[15];
  const float* irW1 = (const float*)d_in[16];
  const float* irb1 = (const float*)d_in[17];
  const float* irW2 = (const float*)d_in[18];
  const float* irb2 = (const float*)d_in[19];
  const float* lng = (const float*)d_in[20];
  const float* lnb = (const float*)d_in[21];
  const float* Zm = (const float*)d_in[22];

  float* ws = (float*)d_ws;
  float* sent = ws;                  // 524288
  float* qsum = sent + 524288;       // 8192
  float* e1 = qsum + 8192;           // 262144
  float* e2 = e1 + 262144;           // 262144
  float* r1 = e2 + 262144;           // 131072
  float* r2 = r1 + 131072;           // 131072
  float* r3 = r2 + 131072;           // 131072
  float* qe1 = r3 + 131072;          // 4096
  float* qe2s = qe1 + 4096;          // 4096 (unused ie head 1)
  float* qr1 = qe2s + 4096;          // 2048
  float* qr2 = qr1 + 2048;           // 2048
  float* qr3 = qr2 + 2048;           // 2048
  float* isum = qr3 + 2048;          // 4096
  float* Wcoef = isum + 4096;        // 9*64*4096 = 2359296
  float4* acd = (float4*)(Wcoef + 2359296);  // 64*64*64 float4 = 4 MB
  float* outF = (float*)d_out;

  k_embed<<<B_ * S_ + B_, 128, 0, stream>>>(story, query, we, pe, sent, qsum);
  k_mlp<<<64 * 5, 256, 0, stream>>>(sent, ueW1, ueb1, ueW2, ueb2,
                                    urW1, urb1, urW2, urb2, e1, e2, r1, r2, r3);
  k_mlp<<<5, 256, 0, stream>>>(qsum, ieW1, ieb1, ieW2, ieb2,
                               irW1, irb1, irW2, irb2, qe1, qe2s, qr1, qr2, qr3);
  k_gram<<<64 * 9, 256, 0, stream>>>(e1, e2, r1, r2, r3, Wcoef);
  k_scan<<<B_, 64, 0, stream>>>(e1, e2, Wcoef, acd);
  k_infer<<<B_, 256, 0, stream>>>(acd, e1, e2, r1, r2, r3, qe1, qr1, qr2, qr3,
                                  lng, lnb, isum);
  k_final<<<V_ / 64, 256, 0, stream>>>(isum, Zm, outF);
}

// Round 4
// 450.285 us; speedup vs baseline: 1.1731x; 1.1731x over previous
//
#include <hip/hip_runtime.h>
#include <math.h>

// Problem constants
#define B_   64
#define S_   64
#define W_   12
#define V_   32000
#define SYM_ 128
#define HID_ 256
#define E_   64
#define R_   32

// ---------------------------------------------------------------------------
// K1: sentence / query embedding sums
// ---------------------------------------------------------------------------
__global__ __launch_bounds__(128) void k_embed(
    const int* __restrict__ story, const int* __restrict__ query,
    const float* __restrict__ we, const float* __restrict__ pe,
    float* __restrict__ sent, float* __restrict__ qsum) {
  int blk = blockIdx.x;
  int e = threadIdx.x;
  if (blk < B_ * S_) {
    const int* idx = story + blk * W_;
    float acc = 0.f;
#pragma unroll
    for (int w = 0; w < W_; ++w)
      acc = fmaf(we[(long)idx[w] * SYM_ + e], pe[w * SYM_ + e], acc);
    sent[blk * SYM_ + e] = acc;
  } else {
    int b = blk - B_ * S_;
    const int* idx = query + b * W_;
    float acc = 0.f;
#pragma unroll
    for (int w = 0; w < W_; ++w)
      acc = fmaf(we[(long)idx[w] * SYM_ + e], pe[w * SYM_ + e], acc);
    qsum[b * SYM_ + e] = acc;
  }
}

// ---------------------------------------------------------------------------
// K2: two-layer MLP heads (unchanged)
// ---------------------------------------------------------------------------
__global__ __launch_bounds__(256) void k_mlp(
    const float* __restrict__ X,
    const float* __restrict__ eW1, const float* __restrict__ eb1,
    const float* __restrict__ eW2, const float* __restrict__ eb2,
    const float* __restrict__ rW1, const float* __restrict__ rb1,
    const float* __restrict__ rW2, const float* __restrict__ rb2,
    float* __restrict__ oE0, float* __restrict__ oE1,
    float* __restrict__ oR0, float* __restrict__ oR1, float* __restrict__ oR2) {
  __shared__ float XT[128 * 68];
  __shared__ float HT[64 * 68];

  int h = blockIdx.x % 5;
  int tile = blockIdx.x / 5;
  int rowbase = tile * 64;
  bool isE = (h < 2);
  const float* W1 = isE ? eW1 + h * (SYM_ * HID_) : rW1 + (h - 2) * (SYM_ * HID_);
  const float* b1 = isE ? eb1 + h * HID_ : rb1 + (h - 2) * HID_;
  const float* W2 = isE ? eW2 + h * (HID_ * E_) : rW2 + (h - 2) * (HID_ * R_);
  const float* b2 = isE ? eb2 + h * E_ : rb2 + (h - 2) * R_;
  float* out = (h == 0) ? oE0 : (h == 1) ? oE1 : (h == 2) ? oR0 : (h == 3) ? oR1 : oR2;

  int tid = threadIdx.x;
  for (int i = tid; i < 64 * 128; i += 256) {
    int row = i >> 7, k = i & 127;
    XT[k * 68 + row] = X[(long)(rowbase + row) * SYM_ + k];
  }
  __syncthreads();

  int tr = tid >> 4, tc = tid & 15;
  float accE[4][4] = {};
  float accR[4][2] = {};

  for (int p = 0; p < 4; ++p) {
    int cbase = p * 64;
    float4 b1v = *(const float4*)(b1 + cbase + 4 * tc);
    float a[4][4] = {};
#pragma unroll 4
    for (int k = 0; k < 128; ++k) {
      float4 xa = *(const float4*)&XT[k * 68 + 4 * tr];
      float4 wb = *(const float4*)(W1 + k * HID_ + cbase + 4 * tc);
      float xs[4] = {xa.x, xa.y, xa.z, xa.w};
      float wsv[4] = {wb.x, wb.y, wb.z, wb.w};
#pragma unroll
      for (int i = 0; i < 4; ++i)
#pragma unroll
        for (int j = 0; j < 4; ++j) a[i][j] = fmaf(xs[i], wsv[j], a[i][j]);
    }
    __syncthreads();
    float b1s[4] = {b1v.x, b1v.y, b1v.z, b1v.w};
#pragma unroll
    for (int i = 0; i < 4; ++i)
#pragma unroll
      for (int j = 0; j < 4; ++j)
        HT[(4 * tc + j) * 68 + 4 * tr + i] = tanhf(a[i][j] + b1s[j]);
    __syncthreads();
    if (isE) {
#pragma unroll 2
      for (int c = 0; c < 64; ++c) {
        float4 h4 = *(const float4*)&HT[c * 68 + 4 * tr];
        float4 w4 = *(const float4*)(W2 + (long)(cbase + c) * E_ + 4 * tc);
        float hs[4] = {h4.x, h4.y, h4.z, h4.w};
        float wv[4] = {w4.x, w4.y, w4.z, w4.w};
#pragma unroll
        for (int i = 0; i < 4; ++i)
#pragma unroll
          for (int j = 0; j < 4; ++j) accE[i][j] = fmaf(hs[i], wv[j], accE[i][j]);
      }
    } else {
#pragma unroll 2
      for (int c = 0; c < 64; ++c) {
        float4 h4 = *(const float4*)&HT[c * 68 + 4 * tr];
        float2 w2 = *(const float2*)(W2 + (long)(cbase + c) * R_ + 2 * tc);
        float hs[4] = {h4.x, h4.y, h4.z, h4.w};
#pragma unroll
        for (int i = 0; i < 4; ++i) {
          accR[i][0] = fmaf(hs[i], w2.x, accR[i][0]);
          accR[i][1] = fmaf(hs[i], w2.y, accR[i][1]);
        }
      }
    }
  }
  if (isE) {
    float4 b2v = *(const float4*)(b2 + 4 * tc);
#pragma unroll
    for (int i = 0; i < 4; ++i) {
      float4 o4 = make_float4(accE[i][0] + b2v.x, accE[i][1] + b2v.y,
                              accE[i][2] + b2v.z, accE[i][3] + b2v.w);
      *(float4*)(out + (long)(rowbase + 4 * tr + i) * E_ + 4 * tc) = o4;
    }
  } else {
    float2 b2v = *(const float2*)(b2 + 2 * tc);
#pragma unroll
    for (int i = 0; i < 4; ++i) {
      float2 o2 = make_float2(accR[i][0] + b2v.x, accR[i][1] + b2v.y);
      *(float2*)(out + (long)(rowbase + 4 * tr + i) * R_ + 2 * tc) = o2;
    }
  }
}

// ---------------------------------------------------------------------------
// K_gram: W[b,m,s,j] = (sE_s . jE_j) * (sR_s . jR_j)   (unchanged)
// ---------------------------------------------------------------------------
__global__ __launch_bounds__(256) void k_gram(
    const float* __restrict__ e1, const float* __restrict__ e2,
    const float* __restrict__ r1, const float* __restrict__ r2,
    const float* __restrict__ r3, float* __restrict__ Wc) {
  int b = blockIdx.x / 9, m = blockIdx.x % 9;
  const float* sE = ((m < 6) ? e1 : e2) + (long)b * S_ * E_;
  const float* jE = ((m == 2 || m == 5 || m == 8) ? e2 : e1) + (long)b * S_ * E_;
  int sk = m / 3, jk = m % 3;
  const float* sR = ((sk == 0) ? r1 : (sk == 1) ? r2 : r3) + (long)b * S_ * R_;
  const float* jR = ((jk == 0) ? r1 : (jk == 1) ? r2 : r3) + (long)b * S_ * R_;

  __shared__ float Es[64][68], Ej[64][68], Rs[64][36], Rj[64][36];
  int tid = threadIdx.x;
  for (int i = tid; i < 1024; i += 256) {
    int row = i >> 4, c = i & 15;
    *(float4*)&Es[row][4 * c] = *(const float4*)(sE + row * 64 + 4 * c);
    *(float4*)&Ej[row][4 * c] = *(const float4*)(jE + row * 64 + 4 * c);
  }
  for (int i = tid; i < 512; i += 256) {
    int row = i >> 3, c = i & 7;
    *(float4*)&Rs[row][4 * c] = *(const float4*)(sR + row * 32 + 4 * c);
    *(float4*)&Rj[row][4 * c] = *(const float4*)(jR + row * 32 + 4 * c);
  }
  __syncthreads();

  int s0 = (tid >> 4) * 4, j0 = (tid & 15) * 4;
  float ed[4][4] = {}, rd[4][4] = {};
#pragma unroll 4
  for (int k = 0; k < 16; ++k) {
    float4 es[4], ej[4];
#pragma unroll
    for (int i = 0; i < 4; ++i) {
      es[i] = *(const float4*)&Es[s0 + i][4 * k];
      ej[i] = *(const float4*)&Ej[j0 + i][4 * k];
    }
#pragma unroll
    for (int i = 0; i < 4; ++i)
#pragma unroll
      for (int j = 0; j < 4; ++j)
        ed[i][j] = fmaf(es[i].x, ej[j].x, fmaf(es[i].y, ej[j].y,
                   fmaf(es[i].z, ej[j].z, fmaf(es[i].w, ej[j].w, ed[i][j]))));
  }
#pragma unroll 4
  for (int k = 0; k < 8; ++k) {
    float4 rs[4], rj[4];
#pragma unroll
    for (int i = 0; i < 4; ++i) {
      rs[i] = *(const float4*)&Rs[s0 + i][4 * k];
      rj[i] = *(const float4*)&Rj[j0 + i][4 * k];
    }
#pragma unroll
    for (int i = 0; i < 4; ++i)
#pragma unroll
      for (int j = 0; j < 4; ++j)
        rd[i][j] = fmaf(rs[i].x, rj[j].x, fmaf(rs[i].y, rj[j].y,
                   fmaf(rs[i].z, rj[j].z, fmaf(rs[i].w, rj[j].w, rd[i][j]))));
  }
  float* wout = Wc + (((long)(b * 9 + m) * 64) * 64);
#pragma unroll
  for (int i = 0; i < 4; ++i) {
    float4 o4 = make_float4(ed[i][0] * rd[i][0], ed[i][1] * rd[i][1],
                            ed[i][2] * rd[i][2], ed[i][3] * rd[i][3]);
    *(float4*)(wout + (s0 + i) * 64 + j0) = o4;
  }
}

// ---------------------------------------------------------------------------
// K_scan v3: one wave per (b, 16-f group) -> 256 blocks, 1 wave each.
// Lane = js*16 + fi: js = j-slice (16 j's), fi = f within group.
// Full 64-j dot every step (hist pre-zeroed => j>=s terms contribute 0),
// shfl_xor(16,32) combines the 4 j-slices. W coefficients staged per
// 16-step chunk into LDS interleaved [sl][j][m] (stride 11).
// ---------------------------------------------------------------------------
__global__ __launch_bounds__(64) void k_scan(
    const float* __restrict__ e1, const float* __restrict__ e2,
    const float* __restrict__ Wc, float4* __restrict__ acd) {
  __shared__ float4 hist[64 * 17];     // hist[j*17+fi]
  __shared__ float Wl[16 * 64 * 11];   // Wl[(sl*64+j)*11+m]
  int b = blockIdx.x >> 2;
  int fg = blockIdx.x & 3;
  int lane = threadIdx.x;
  int fi = lane & 15;
  int js = lane >> 4;
  int f = fg * 16 + fi;
  const float* Wb = Wc + (long)b * 9 * 4096;
  const float* e1b = e1 + (long)b * 4096;
  const float* e2b = e2 + (long)b * 4096;

  for (int j = js; j < 64; j += 4)
    hist[j * 17 + fi] = make_float4(0.f, 0.f, 0.f, 0.f);
  __syncthreads();

  for (int ch = 0; ch < 4; ++ch) {
    int s0 = ch * 16;
    // stage W chunk: 9 planes x 16 rows x 64 j  (float4 over j)
    for (int idx = lane; idx < 9 * 16 * 16; idx += 64) {
      int m = idx >> 8;                 // / 256
      int rem = idx & 255;
      int sl = rem >> 4, j4 = (rem & 15) * 4;
      float4 w4 = *(const float4*)(Wb + m * 4096 + (s0 + sl) * 64 + j4);
      float* dst = &Wl[(sl * 64 + j4) * 11 + m];
      dst[0] = w4.x; dst[11] = w4.y; dst[22] = w4.z; dst[33] = w4.w;
    }
    __syncthreads();
    for (int sl = 0; sl < 16; ++sl) {
      int s = s0 + sl;
      float e1sf = e1b[s * 64 + f];
      float e2sf = e2b[s * 64 + f];
      float aw = 0.f, cw = 0.f, dw = 0.f;
      float am = 0.f, cm = 0.f, dm = 0.f;
      float ab = 0.f, cb = 0.f, db = 0.f;
#pragma unroll
      for (int jj = 0; jj < 16; ++jj) {
        int j = js * 16 + jj;
        float4 h = hist[j * 17 + fi];
        const float* w = &Wl[(sl * 64 + j) * 11];
        aw = fmaf(w[0], h.x, aw);
        cw = fmaf(w[1], h.y, cw);
        dw = fmaf(w[2], h.z, dw);
        am = fmaf(w[3], h.x, am);
        cm = fmaf(w[4], h.y, cm);
        dm = fmaf(w[5], h.z, dm);
        ab = fmaf(w[6], h.x, ab);
        cb = fmaf(w[7], h.y, cb);
        db = fmaf(w[8], h.z, db);
      }
      float wh = (aw + cw) + dw;
      float mh = (am + cm) + dm;
      float bh = (ab + cb) + db;
      wh += __shfl_xor(wh, 16, 64); wh += __shfl_xor(wh, 32, 64);
      mh += __shfl_xor(mh, 16, 64); mh += __shfl_xor(mh, 32, 64);
      bh += __shfl_xor(bh, 16, 64); bh += __shfl_xor(bh, 32, 64);
      float a = e2sf - wh;
      float c = wh - mh;
      float d = e1sf - bh;
      if (js == 0) hist[s * 17 + fi] = make_float4(a, c, d, 0.f);
      __syncthreads();
    }
  }
  // write acd[b][s][f]
  for (int s = js; s < 64; s += 4)
    acd[((long)b * 64 + s) * 64 + f] = hist[s * 17 + fi];
}

// ---------------------------------------------------------------------------
// K_infer (factored, unchanged)
// ---------------------------------------------------------------------------
__global__ __launch_bounds__(256) void k_infer(
    const float4* __restrict__ acd,
    const float* __restrict__ e1, const float* __restrict__ e2,
    const float* __restrict__ r1, const float* __restrict__ r2,
    const float* __restrict__ r3,
    const float* __restrict__ qe1, const float* __restrict__ qr1,
    const float* __restrict__ qr2, const float* __restrict__ qr3,
    const float* __restrict__ lng, const float* __restrict__ lnb,
    float* __restrict__ isum) {
  int b = blockIdx.x, tid = threadIdx.x;
  __shared__ float4 hist[64 * 64];
  __shared__ float vlds[9 * 64];
  __shared__ float ivec[64];
  __shared__ float u1s[64], u2s[64];
  __shared__ float dsc[64];

  for (int i = tid; i < 4096; i += 256) hist[i] = acd[(long)b * 4096 + i];
  for (int idx = tid; idx < 576; idx += 256) {
    int pk = idx >> 6, j = idx & 63;
    int p = pk / 3, k = pk % 3;
    const float* rv = ((k == 0) ? r1 : (k == 1) ? r2 : r3) + ((long)b * 64 + j) * 32;
    const float* q = ((p == 0) ? qr1 : (p == 1) ? qr2 : qr3) + b * 32;
    float acc = 0.f;
#pragma unroll
    for (int t = 0; t < 8; ++t) {
      float4 rv4 = *(const float4*)(rv + 4 * t);
      float4 q4 = *(const float4*)(q + 4 * t);
      acc = fmaf(rv4.x, q4.x, fmaf(rv4.y, q4.y,
            fmaf(rv4.z, q4.z, fmaf(rv4.w, q4.w, acc))));
    }
    vlds[pk * 64 + j] = acc;
  }
  if (tid < 64) ivec[tid] = qe1[b * 64 + tid];
  __syncthreads();

  float isacc = 0.f;
  int f = tid >> 2, q = tid & 3;
  for (int p = 0; p < 3; ++p) {
    if (tid < 128) {
      int which = tid >> 6, j = tid & 63;
      const float* erow = (which ? e2 : e1) + ((long)b * 64 + j) * 64;
      const float4* iv4 = (const float4*)ivec;
      float acc = 0.f;
#pragma unroll
      for (int t = 0; t < 16; ++t) {
        float4 ev = *(const float4*)(erow + 4 * t);
        float4 c4 = iv4[t];
        acc = fmaf(ev.x, c4.x, fmaf(ev.y, c4.y,
              fmaf(ev.z, c4.z, fmaf(ev.w, c4.w, acc))));
      }
      if (which) u2s[j] = acc; else u1s[j] = acc;
    }
    __syncthreads();
    float part = 0.f;
#pragma unroll 4
    for (int jj = 0; jj < 16; ++jj) {
      int j = q * 16 + jj;
      float4 h = hist[j * 64 + f];
      float ca = u1s[j] * vlds[(p * 3 + 0) * 64 + j];
      float cc = u1s[j] * vlds[(p * 3 + 1) * 64 + j];
      float cd = u2s[j] * vlds[(p * 3 + 2) * 64 + j];
      part = fmaf(ca, h.x, fmaf(cc, h.y, fmaf(cd, h.z, part)));
    }
    part += __shfl_xor(part, 1, 64);
    part += __shfl_xor(part, 2, 64);
    if (q == 0) dsc[f] = part;
    __syncthreads();
    if (tid < 64) {
      float v = dsc[tid];
      float mu = v;
#pragma unroll
      for (int mm = 1; mm <= 32; mm <<= 1) mu += __shfl_xor(mu, mm, 64);
      mu *= (1.f / 64.f);
      float d = v - mu;
      float vr = d * d;
#pragma unroll
      for (int mm = 1; mm <= 32; mm <<= 1) vr += __shfl_xor(vr, mm, 64);
      vr *= (1.f / 64.f);
      float iv = d * (1.f / sqrtf(vr + 1e-5f)) * lng[p * 64 + tid] + lnb[p * 64 + tid];
      ivec[tid] = iv;
      isacc += iv;
    }
    __syncthreads();
  }
  if (tid < 64) isum[b * 64 + tid] = isacc;
}

// ---------------------------------------------------------------------------
// K5: out[b,v] = sum_e isum[b,e] * Z[e,v]   (unchanged)
// ---------------------------------------------------------------------------
__global__ __launch_bounds__(256) void k_final(
    const float* __restrict__ isum, const float* __restrict__ Zm,
    float* __restrict__ out) {
  __shared__ float isT[64 * 68];
  int tid = threadIdx.x;
  for (int i = tid; i < 4096; i += 256) {
    int bb = i >> 6, e = i & 63;
    isT[e * 68 + bb] = isum[i];
  }
  __syncthreads();
  int tr = tid >> 4, tc = tid & 15;
  int v0 = blockIdx.x * 64 + tc * 4;
  float acc[4][4] = {};
#pragma unroll 2
  for (int e = 0; e < 64; ++e) {
    float4 a4 = *(const float4*)&isT[e * 68 + 4 * tr];
    float4 z4 = *(const float4*)(Zm + (long)e * V_ + v0);
    float as[4] = {a4.x, a4.y, a4.z, a4.w};
    float zs[4] = {z4.x, z4.y, z4.z, z4.w};
#pragma unroll
    for (int i = 0; i < 4; ++i)
#pragma unroll
      for (int j = 0; j < 4; ++j) acc[i][j] = fmaf(as[i], zs[j], acc[i][j]);
  }
#pragma unroll
  for (int i = 0; i < 4; ++i) {
    float4 o4 = make_float4(acc[i][0], acc[i][1], acc[i][2], acc[i][3]);
    *(float4*)(out + (long)(4 * tr + i) * V_ + v0) = o4;
  }
}

// ---------------------------------------------------------------------------
extern "C" void kernel_launch(void* const* d_in, const int* in_sizes, int n_in,
                              void* d_out, int out_size, void* d_ws, size_t ws_size,
                              hipStream_t stream) {
  const int* story = (const int*)d_in[0];
  const int* query = (const int*)d_in[1];
  const float* we = (const float*)d_in[2];
  const float* pe = (const float*)d_in[3];
  const float* ueW1 = (const float*)d_in[4];
  const float* ueb1 = (const float*)d_in[5];
  const float* ueW2 = (const float*)d_in[6];
  const float* ueb2 = (const float*)d_in[7];
  const float* urW1 = (const float*)d_in[8];
  const float* urb1 = (const float*)d_in[9];
  const float* urW2 = (const float*)d_in[10];
  const float* urb2 = (const float*)d_in[11];
  const float* ieW1 = (const float*)d_in[12];
  const float* ieb1 = (const float*)d_in[13];
  const float* ieW2 = (const float*)d_in[14];
  const float* ieb2 = (const float*)d_in[15];
  const float* irW1 = (const float*)d_in[16];
  const float* irb1 = (const float*)d_in[17];
  const float* irW2 = (const float*)d_in[18];
  const float* irb2 = (const float*)d_in[19];
  const float* lng = (const float*)d_in[20];
  const float* lnb = (const float*)d_in[21];
  const float* Zm = (const float*)d_in[22];

  float* ws = (float*)d_ws;
  float* sent = ws;                  // 524288
  float* qsum = sent + 524288;       // 8192
  float* e1 = qsum + 8192;           // 262144
  float* e2 = e1 + 262144;           // 262144
  float* r1 = e2 + 262144;           // 131072
  float* r2 = r1 + 131072;           // 131072
  float* r3 = r2 + 131072;           // 131072
  float* qe1 = r3 + 131072;          // 4096
  float* qe2s = qe1 + 4096;          // 4096 (unused ie head 1)
  float* qr1 = qe2s + 4096;          // 2048
  float* qr2 = qr1 + 2048;           // 2048
  float* qr3 = qr2 + 2048;           // 2048
  float* isum = qr3 + 2048;          // 4096
  float* Wcoef = isum + 4096;        // 9*64*4096 = 2359296
  float4* acd = (float4*)(Wcoef + 2359296);  // 64*64*64 float4 = 4 MB
  float* outF = (float*)d_out;

  k_embed<<<B_ * S_ + B_, 128, 0, stream>>>(story, query, we, pe, sent, qsum);
  k_mlp<<<64 * 5, 256, 0, stream>>>(sent, ueW1, ueb1, ueW2, ueb2,
                                    urW1, urb1, urW2, urb2, e1, e2, r1, r2, r3);
  k_mlp<<<5, 256, 0, stream>>>(qsum, ieW1, ieb1, ieW2, ieb2,
                               irW1, irb1, irW2, irb2, qe1, qe2s, qr1, qr2, qr3);
  k_gram<<<64 * 9, 256, 0, stream>>>(e1, e2, r1, r2, r3, Wcoef);
  k_scan<<<B_ * 4, 64, 0, stream>>>(e1, e2, Wcoef, acd);
  k_infer<<<B_, 256, 0, stream>>>(acd, e1, e2, r1, r2, r3, qe1, qr1, qr2, qr3,
                                  lng, lnb, isum);
  k_final<<<V_ / 64, 256, 0, stream>>>(isum, Zm, outF);
}

// Round 5
// 330.270 us; speedup vs baseline: 1.5994x; 1.3634x over previous
//
#include <hip/hip_runtime.h>
#include <math.h>

// Problem constants
#define B_   64
#define S_   64
#define W_   12
#define V_   32000
#define SYM_ 128
#define HID_ 256
#define E_   64
#define R_   32

// ---------------------------------------------------------------------------
// K1: embedding sums for story (rows 0..4095) and query (rows 4096..4159)
// into one X buffer [4160, 128].
// ---------------------------------------------------------------------------
__global__ __launch_bounds__(128) void k_embed(
    const int* __restrict__ story, const int* __restrict__ query,
    const float* __restrict__ we, const float* __restrict__ pe,
    float* __restrict__ X) {
  int row = blockIdx.x;
  int e = threadIdx.x;
  const int* idx = (row < 4096) ? story + row * W_ : query + (row - 4096) * W_;
  float acc = 0.f;
#pragma unroll
  for (int w = 0; w < W_; ++w)
    acc = fmaf(we[(long)idx[w] * SYM_ + e], pe[w * SYM_ + e], acc);
  X[row * SYM_ + e] = acc;
}

// ---------------------------------------------------------------------------
// K2: two-layer MLP heads over 4160 rows. 32-row tiles x 5 heads = 650 blocks.
// Tiles >=128 (rows 4096+) use inference weights. Odd LDS strides (33).
// Thread (tr=tid>>4, tc=tid&15) computes rows {2tr,2tr+1} x 4 cols.
// ---------------------------------------------------------------------------
__global__ __launch_bounds__(256) void k_mlp(
    const float* __restrict__ X,
    const float* __restrict__ ueW1, const float* __restrict__ ueb1,
    const float* __restrict__ ueW2, const float* __restrict__ ueb2,
    const float* __restrict__ urW1, const float* __restrict__ urb1,
    const float* __restrict__ urW2, const float* __restrict__ urb2,
    const float* __restrict__ ieW1, const float* __restrict__ ieb1,
    const float* __restrict__ ieW2, const float* __restrict__ ieb2,
    const float* __restrict__ irW1, const float* __restrict__ irb1,
    const float* __restrict__ irW2, const float* __restrict__ irb2,
    float* __restrict__ oE0, float* __restrict__ oE1,
    float* __restrict__ oR0, float* __restrict__ oR1, float* __restrict__ oR2) {
  __shared__ float XT[128 * 33];  // [k][row], 32 rows + 1 pad
  __shared__ float HT[64 * 33];   // [c][row]

  int h = blockIdx.x % 5;
  int tile = blockIdx.x / 5;
  int rowbase = tile * 32;
  bool isQ = (rowbase >= 4096);
  bool isE = (h < 2);
  const float* eW1 = isQ ? ieW1 : ueW1;
  const float* eb1 = isQ ? ieb1 : ueb1;
  const float* eW2 = isQ ? ieW2 : ueW2;
  const float* eb2 = isQ ? ieb2 : ueb2;
  const float* rW1 = isQ ? irW1 : urW1;
  const float* rb1 = isQ ? irb1 : urb1;
  const float* rW2 = isQ ? irW2 : urW2;
  const float* rb2 = isQ ? irb2 : urb2;
  const float* W1 = isE ? eW1 + h * (SYM_ * HID_) : rW1 + (h - 2) * (SYM_ * HID_);
  const float* b1 = isE ? eb1 + h * HID_ : rb1 + (h - 2) * HID_;
  const float* W2 = isE ? eW2 + h * (HID_ * E_) : rW2 + (h - 2) * (HID_ * R_);
  const float* b2 = isE ? eb2 + h * E_ : rb2 + (h - 2) * R_;
  float* out = (h == 0) ? oE0 : (h == 1) ? oE1 : (h == 2) ? oR0 : (h == 3) ? oR1 : oR2;

  int tid = threadIdx.x;
  // stage X tile transposed: 32 rows x 128 k
  for (int i = tid; i < 32 * 128; i += 256) {
    int row = i >> 7, k = i & 127;
    XT[k * 33 + row] = X[(long)(rowbase + row) * SYM_ + k];
  }
  __syncthreads();

  int tr = tid >> 4, tc = tid & 15;
  float accE0[4] = {}, accE1[4] = {};
  float accR0[2] = {}, accR1[2] = {};

  for (int p = 0; p < 4; ++p) {
    int cbase = p * 64;
    float4 b1v = *(const float4*)(b1 + cbase + 4 * tc);
    float a0[4] = {}, a1[4] = {};
#pragma unroll 8
    for (int k = 0; k < 128; ++k) {
      float x0 = XT[k * 33 + 2 * tr];
      float x1 = XT[k * 33 + 2 * tr + 1];
      float4 wb = *(const float4*)(W1 + k * HID_ + cbase + 4 * tc);
      a0[0] = fmaf(x0, wb.x, a0[0]); a0[1] = fmaf(x0, wb.y, a0[1]);
      a0[2] = fmaf(x0, wb.z, a0[2]); a0[3] = fmaf(x0, wb.w, a0[3]);
      a1[0] = fmaf(x1, wb.x, a1[0]); a1[1] = fmaf(x1, wb.y, a1[1]);
      a1[2] = fmaf(x1, wb.z, a1[2]); a1[3] = fmaf(x1, wb.w, a1[3]);
    }
    __syncthreads();  // previous pass done with HT
    float b1s[4] = {b1v.x, b1v.y, b1v.z, b1v.w};
#pragma unroll
    for (int j = 0; j < 4; ++j) {
      HT[(4 * tc + j) * 33 + 2 * tr] = tanhf(a0[j] + b1s[j]);
      HT[(4 * tc + j) * 33 + 2 * tr + 1] = tanhf(a1[j] + b1s[j]);
    }
    __syncthreads();
    if (isE) {
#pragma unroll 4
      for (int c = 0; c < 64; ++c) {
        float h0 = HT[c * 33 + 2 * tr];
        float h1 = HT[c * 33 + 2 * tr + 1];
        float4 w4 = *(const float4*)(W2 + (long)(cbase + c) * E_ + 4 * tc);
        accE0[0] = fmaf(h0, w4.x, accE0[0]); accE0[1] = fmaf(h0, w4.y, accE0[1]);
        accE0[2] = fmaf(h0, w4.z, accE0[2]); accE0[3] = fmaf(h0, w4.w, accE0[3]);
        accE1[0] = fmaf(h1, w4.x, accE1[0]); accE1[1] = fmaf(h1, w4.y, accE1[1]);
        accE1[2] = fmaf(h1, w4.z, accE1[2]); accE1[3] = fmaf(h1, w4.w, accE1[3]);
      }
    } else {
#pragma unroll 4
      for (int c = 0; c < 64; ++c) {
        float h0 = HT[c * 33 + 2 * tr];
        float h1 = HT[c * 33 + 2 * tr + 1];
        float2 w2 = *(const float2*)(W2 + (long)(cbase + c) * R_ + 2 * tc);
        accR0[0] = fmaf(h0, w2.x, accR0[0]); accR0[1] = fmaf(h0, w2.y, accR0[1]);
        accR1[0] = fmaf(h1, w2.x, accR1[0]); accR1[1] = fmaf(h1, w2.y, accR1[1]);
      }
    }
  }
  int r0 = rowbase + 2 * tr;
  if (isE) {
    float4 b2v = *(const float4*)(b2 + 4 * tc);
    *(float4*)(out + (long)r0 * E_ + 4 * tc) =
        make_float4(accE0[0] + b2v.x, accE0[1] + b2v.y, accE0[2] + b2v.z, accE0[3] + b2v.w);
    *(float4*)(out + (long)(r0 + 1) * E_ + 4 * tc) =
        make_float4(accE1[0] + b2v.x, accE1[1] + b2v.y, accE1[2] + b2v.z, accE1[3] + b2v.w);
  } else {
    float2 b2v = *(const float2*)(b2 + 2 * tc);
    *(float2*)(out + (long)r0 * R_ + 2 * tc) =
        make_float2(accR0[0] + b2v.x, accR0[1] + b2v.y);
    *(float2*)(out + (long)(r0 + 1) * R_ + 2 * tc) =
        make_float2(accR1[0] + b2v.x, accR1[1] + b2v.y);
  }
}

// ---------------------------------------------------------------------------
// K_gram: W[b,m,s,j] = (sE_s . jE_j) * (sR_s . jR_j)   (unchanged)
// ---------------------------------------------------------------------------
__global__ __launch_bounds__(256) void k_gram(
    const float* __restrict__ e1, const float* __restrict__ e2,
    const float* __restrict__ r1, const float* __restrict__ r2,
    const float* __restrict__ r3, float* __restrict__ Wc) {
  int b = blockIdx.x / 9, m = blockIdx.x % 9;
  const float* sE = ((m < 6) ? e1 : e2) + (long)b * S_ * E_;
  const float* jE = ((m == 2 || m == 5 || m == 8) ? e2 : e1) + (long)b * S_ * E_;
  int sk = m / 3, jk = m % 3;
  const float* sR = ((sk == 0) ? r1 : (sk == 1) ? r2 : r3) + (long)b * S_ * R_;
  const float* jR = ((jk == 0) ? r1 : (jk == 1) ? r2 : r3) + (long)b * S_ * R_;

  __shared__ float Es[64][68], Ej[64][68], Rs[64][36], Rj[64][36];
  int tid = threadIdx.x;
  for (int i = tid; i < 1024; i += 256) {
    int row = i >> 4, c = i & 15;
    *(float4*)&Es[row][4 * c] = *(const float4*)(sE + row * 64 + 4 * c);
    *(float4*)&Ej[row][4 * c] = *(const float4*)(jE + row * 64 + 4 * c);
  }
  for (int i = tid; i < 512; i += 256) {
    int row = i >> 3, c = i & 7;
    *(float4*)&Rs[row][4 * c] = *(const float4*)(sR + row * 32 + 4 * c);
    *(float4*)&Rj[row][4 * c] = *(const float4*)(jR + row * 32 + 4 * c);
  }
  __syncthreads();

  int s0 = (tid >> 4) * 4, j0 = (tid & 15) * 4;
  float ed[4][4] = {}, rd[4][4] = {};
#pragma unroll 4
  for (int k = 0; k < 16; ++k) {
    float4 es[4], ej[4];
#pragma unroll
    for (int i = 0; i < 4; ++i) {
      es[i] = *(const float4*)&Es[s0 + i][4 * k];
      ej[i] = *(const float4*)&Ej[j0 + i][4 * k];
    }
#pragma unroll
    for (int i = 0; i < 4; ++i)
#pragma unroll
      for (int j = 0; j < 4; ++j)
        ed[i][j] = fmaf(es[i].x, ej[j].x, fmaf(es[i].y, ej[j].y,
                   fmaf(es[i].z, ej[j].z, fmaf(es[i].w, ej[j].w, ed[i][j]))));
  }
#pragma unroll 4
  for (int k = 0; k < 8; ++k) {
    float4 rs[4], rj[4];
#pragma unroll
    for (int i = 0; i < 4; ++i) {
      rs[i] = *(const float4*)&Rs[s0 + i][4 * k];
      rj[i] = *(const float4*)&Rj[j0 + i][4 * k];
    }
#pragma unroll
    for (int i = 0; i < 4; ++i)
#pragma unroll
      for (int j = 0; j < 4; ++j)
        rd[i][j] = fmaf(rs[i].x, rj[j].x, fmaf(rs[i].y, rj[j].y,
                   fmaf(rs[i].z, rj[j].z, fmaf(rs[i].w, rj[j].w, rd[i][j]))));
  }
  float* wout = Wc + (((long)(b * 9 + m) * 64) * 64);
#pragma unroll
  for (int i = 0; i < 4; ++i) {
    float4 o4 = make_float4(ed[i][0] * rd[i][0], ed[i][1] * rd[i][1],
                            ed[i][2] * rd[i][2], ed[i][3] * rd[i][3]);
    *(float4*)(wout + (s0 + i) * 64 + j0) = o4;
  }
}

// ---------------------------------------------------------------------------
// K_scan v4: grid = B*8 blocks (b, 8-f group), 64 threads (1 wave).
// lane = js*8 + fi: fi = f within group, js = j-slice (8 j's).
// History (a,c,d) entirely in registers (8x3 per lane). Every lane computes
// a,c,d from the butterfly-reduced hats; lane with js==s>>3 keeps them.
// W coefficients staged per 16-step chunk into LDS planar [m][sl][j+pad68].
// ---------------------------------------------------------------------------
#define DOT8(w0, w1, hh) \
  fmaf((w0).x, hh[0], fmaf((w0).y, hh[1], fmaf((w0).z, hh[2], fmaf((w0).w, hh[3], \
  fmaf((w1).x, hh[4], fmaf((w1).y, hh[5], fmaf((w1).z, hh[6], (w1).w * hh[7])))))))

__global__ __launch_bounds__(64) void k_scan(
    const float* __restrict__ e1, const float* __restrict__ e2,
    const float* __restrict__ Wc, float4* __restrict__ acd) {
  __shared__ float Wl[9 * 16 * 68];  // [m][sl][j], row pad to 68
  int b = blockIdx.x >> 3;
  int fg = blockIdx.x & 7;
  int lane = threadIdx.x;
  int fi = lane & 7;
  int js = lane >> 3;
  int f = fg * 8 + fi;
  const float* Wb = Wc + (long)b * 9 * 4096;
  const float* e1b = e1 + (long)b * 4096;
  const float* e2b = e2 + (long)b * 4096;

  float ha[8], hc[8], hd[8];
#pragma unroll
  for (int t = 0; t < 8; ++t) { ha[t] = 0.f; hc[t] = 0.f; hd[t] = 0.f; }

  for (int ch = 0; ch < 4; ++ch) {
    int s0 = ch * 16;
    __syncthreads();
    // stage 9 planes x 16 s-rows x 64 j
    for (int idx = lane; idx < 9 * 16 * 16; idx += 64) {
      int m = idx >> 8;
      int rem = idx & 255;
      int sl = rem >> 4, j4 = (rem & 15) * 4;
      float4 w4 = *(const float4*)(Wb + m * 4096 + (s0 + sl) * 64 + j4);
      *(float4*)&Wl[(m * 16 + sl) * 68 + j4] = w4;
    }
    __syncthreads();
#pragma unroll
    for (int sl = 0; sl < 16; ++sl) {
      int s = s0 + sl;
      float e1sf = e1b[s * 64 + f];
      float e2sf = e2b[s * 64 + f];
      const float* wp = &Wl[sl * 68 + js * 8];
      float4 wa0 = *(const float4*)(wp + 0 * 1088);
      float4 wa1 = *(const float4*)(wp + 0 * 1088 + 4);
      float4 wc0 = *(const float4*)(wp + 1 * 1088);
      float4 wc1 = *(const float4*)(wp + 1 * 1088 + 4);
      float4 wd0 = *(const float4*)(wp + 2 * 1088);
      float4 wd1 = *(const float4*)(wp + 2 * 1088 + 4);
      float4 ma0 = *(const float4*)(wp + 3 * 1088);
      float4 ma1 = *(const float4*)(wp + 3 * 1088 + 4);
      float4 mc0 = *(const float4*)(wp + 4 * 1088);
      float4 mc1 = *(const float4*)(wp + 4 * 1088 + 4);
      float4 md0 = *(const float4*)(wp + 5 * 1088);
      float4 md1 = *(const float4*)(wp + 5 * 1088 + 4);
      float4 ba0 = *(const float4*)(wp + 6 * 1088);
      float4 ba1 = *(const float4*)(wp + 6 * 1088 + 4);
      float4 bc0 = *(const float4*)(wp + 7 * 1088);
      float4 bc1 = *(const float4*)(wp + 7 * 1088 + 4);
      float4 bd0 = *(const float4*)(wp + 8 * 1088);
      float4 bd1 = *(const float4*)(wp + 8 * 1088 + 4);

      float wh = DOT8(wa0, wa1, ha) + DOT8(wc0, wc1, hc) + DOT8(wd0, wd1, hd);
      float mh = DOT8(ma0, ma1, ha) + DOT8(mc0, mc1, hc) + DOT8(md0, md1, hd);
      float bh = DOT8(ba0, ba1, ha) + DOT8(bc0, bc1, hc) + DOT8(bd0, bd1, hd);
      wh += __shfl_xor(wh, 8, 64); wh += __shfl_xor(wh, 16, 64); wh += __shfl_xor(wh, 32, 64);
      mh += __shfl_xor(mh, 8, 64); mh += __shfl_xor(mh, 16, 64); mh += __shfl_xor(mh, 32, 64);
      bh += __shfl_xor(bh, 8, 64); bh += __shfl_xor(bh, 16, 64); bh += __shfl_xor(bh, 32, 64);
      float a = e2sf - wh;
      float c = wh - mh;
      float d = e1sf - bh;
      if (js == (s >> 3)) {
        ha[sl & 7] = a; hc[sl & 7] = c; hd[sl & 7] = d;
      }
    }
  }
  // lane (js,fi) holds (a,c,d) for s = js*8+jj at its f
#pragma unroll
  for (int jj = 0; jj < 8; ++jj) {
    int s = js * 8 + jj;
    acd[((long)b * 64 + s) * 64 + f] = make_float4(ha[jj], hc[jj], hd[jj], 0.f);
  }
}

// ---------------------------------------------------------------------------
// K_infer: per b, i1->i2->i3 from factors; acd read straight from L2
// (coalesced float4). Wave-local reduction over q = lane>>4.
// ---------------------------------------------------------------------------
__global__ __launch_bounds__(256) void k_infer(
    const float4* __restrict__ acd,
    const float* __restrict__ e1, const float* __restrict__ e2,
    const float* __restrict__ r1, const float* __restrict__ r2,
    const float* __restrict__ r3,
    const float* __restrict__ qe1, const float* __restrict__ qr1,
    const float* __restrict__ qr2, const float* __restrict__ qr3,
    const float* __restrict__ lng, const float* __restrict__ lnb,
    float* __restrict__ isum) {
  int b = blockIdx.x, tid = threadIdx.x;
  __shared__ float vlds[9 * 64];
  __shared__ float ivec[64];
  __shared__ float u1s[64], u2s[64];
  __shared__ float dsc[64];
  const float4* ab = acd + (long)b * 4096;

  for (int idx = tid; idx < 576; idx += 256) {
    int pk = idx >> 6, j = idx & 63;
    int p = pk / 3, k = pk % 3;
    const float* rv = ((k == 0) ? r1 : (k == 1) ? r2 : r3) + ((long)b * 64 + j) * 32;
    const float* q = ((p == 0) ? qr1 : (p == 1) ? qr2 : qr3) + b * 32;
    float acc = 0.f;
#pragma unroll
    for (int t = 0; t < 8; ++t) {
      float4 rv4 = *(const float4*)(rv + 4 * t);
      float4 q4 = *(const float4*)(q + 4 * t);
      acc = fmaf(rv4.x, q4.x, fmaf(rv4.y, q4.y,
            fmaf(rv4.z, q4.z, fmaf(rv4.w, q4.w, acc))));
    }
    vlds[pk * 64 + j] = acc;
  }
  if (tid < 64) ivec[tid] = qe1[b * 64 + tid];
  __syncthreads();

  int lane = tid & 63, wv = tid >> 6;
  int fx = wv * 16 + (lane & 15);
  int q = lane >> 4;
  float isacc = 0.f;
  for (int p = 0; p < 3; ++p) {
    if (tid < 128) {
      int which = tid >> 6, j = tid & 63;
      const float* erow = (which ? e2 : e1) + ((long)b * 64 + j) * 64;
      const float4* iv4 = (const float4*)ivec;
      float acc = 0.f;
#pragma unroll
      for (int t = 0; t < 16; ++t) {
        float4 ev = *(const float4*)(erow + 4 * t);
        float4 c4 = iv4[t];
        acc = fmaf(ev.x, c4.x, fmaf(ev.y, c4.y,
              fmaf(ev.z, c4.z, fmaf(ev.w, c4.w, acc))));
      }
      if (which) u2s[j] = acc; else u1s[j] = acc;
    }
    __syncthreads();
    float part = 0.f;
#pragma unroll 4
    for (int jj = 0; jj < 16; ++jj) {
      int j = q * 16 + jj;
      float4 h = ab[j * 64 + fx];
      float ca = u1s[j] * vlds[(p * 3 + 0) * 64 + j];
      float cc = u1s[j] * vlds[(p * 3 + 1) * 64 + j];
      float cd = u2s[j] * vlds[(p * 3 + 2) * 64 + j];
      part = fmaf(ca, h.x, fmaf(cc, h.y, fmaf(cd, h.z, part)));
    }
    part += __shfl_xor(part, 16, 64);
    part += __shfl_xor(part, 32, 64);
    if (q == 0) dsc[fx] = part;
    __syncthreads();
    if (tid < 64) {
      float v = dsc[tid];
      float mu = v;
#pragma unroll
      for (int mm = 1; mm <= 32; mm <<= 1) mu += __shfl_xor(mu, mm, 64);
      mu *= (1.f / 64.f);
      float d = v - mu;
      float vr = d * d;
#pragma unroll
      for (int mm = 1; mm <= 32; mm <<= 1) vr += __shfl_xor(vr, mm, 64);
      vr *= (1.f / 64.f);
      float iv = d * (1.f / sqrtf(vr + 1e-5f)) * lng[p * 64 + tid] + lnb[p * 64 + tid];
      ivec[tid] = iv;
      isacc += iv;
    }
    __syncthreads();
  }
  if (tid < 64) isum[b * 64 + tid] = isacc;
}

// ---------------------------------------------------------------------------
// K5: out[b,v] = sum_e isum[b,e] * Z[e,v]   (unchanged)
// ---------------------------------------------------------------------------
__global__ __launch_bounds__(256) void k_final(
    const float* __restrict__ isum, const float* __restrict__ Zm,
    float* __restrict__ out) {
  __shared__ float isT[64 * 68];
  int tid = threadIdx.x;
  for (int i = tid; i < 4096; i += 256) {
    int bb = i >> 6, e = i & 63;
    isT[e * 68 + bb] = isum[i];
  }
  __syncthreads();
  int tr = tid >> 4, tc = tid & 15;
  int v0 = blockIdx.x * 64 + tc * 4;
  float acc[4][4] = {};
#pragma unroll 2
  for (int e = 0; e < 64; ++e) {
    float4 a4 = *(const float4*)&isT[e * 68 + 4 * tr];
    float4 z4 = *(const float4*)(Zm + (long)e * V_ + v0);
    float as[4] = {a4.x, a4.y, a4.z, a4.w};
    float zs[4] = {z4.x, z4.y, z4.z, z4.w};
#pragma unroll
    for (int i = 0; i < 4; ++i)
#pragma unroll
      for (int j = 0; j < 4; ++j) acc[i][j] = fmaf(as[i], zs[j], acc[i][j]);
  }
#pragma unroll
  for (int i = 0; i < 4; ++i) {
    float4 o4 = make_float4(acc[i][0], acc[i][1], acc[i][2], acc[i][3]);
    *(float4*)(out + (long)(4 * tr + i) * V_ + v0) = o4;
  }
}

// ---------------------------------------------------------------------------
extern "C" void kernel_launch(void* const* d_in, const int* in_sizes, int n_in,
                              void* d_out, int out_size, void* d_ws, size_t ws_size,
                              hipStream_t stream) {
  const int* story = (const int*)d_in[0];
  const int* query = (const int*)d_in[1];
  const float* we = (const float*)d_in[2];
  const float* pe = (const float*)d_in[3];
  const float* ueW1 = (const float*)d_in[4];
  const float* ueb1 = (const float*)d_in[5];
  const float* ueW2 = (const float*)d_in[6];
  const float* ueb2 = (const float*)d_in[7];
  const float* urW1 = (const float*)d_in[8];
  const float* urb1 = (const float*)d_in[9];
  const float* urW2 = (const float*)d_in[10];
  const float* urb2 = (const float*)d_in[11];
  const float* ieW1 = (const float*)d_in[12];
  const float* ieb1 = (const float*)d_in[13];
  const float* ieW2 = (const float*)d_in[14];
  const float* ieb2 = (const float*)d_in[15];
  const float* irW1 = (const float*)d_in[16];
  const float* irb1 = (const float*)d_in[17];
  const float* irW2 = (const float*)d_in[18];
  const float* irb2 = (const float*)d_in[19];
  const float* lng = (const float*)d_in[20];
  const float* lnb = (const float*)d_in[21];
  const float* Zm = (const float*)d_in[22];

  float* ws = (float*)d_ws;
  float* X = ws;                        // 4160*128 = 532480
  float* e1 = X + 532480;               // 4160*64  = 266240
  float* e2 = e1 + 266240;              // 266240
  float* r1 = e2 + 266240;              // 4160*32  = 133120
  float* r2 = r1 + 133120;              // 133120
  float* r3 = r2 + 133120;              // 133120
  float* isum = r3 + 133120;            // 4096
  float* Wcoef = isum + 4096;           // 9*64*4096 = 2359296
  float4* acd = (float4*)(Wcoef + 2359296);  // 64*64*64 float4 = 4 MB
  float* qe1 = e1 + 4096 * 64;
  float* qr1 = r1 + 4096 * 32;
  float* qr2 = r2 + 4096 * 32;
  float* qr3 = r3 + 4096 * 32;
  float* outF = (float*)d_out;

  k_embed<<<4160, 128, 0, stream>>>(story, query, we, pe, X);
  k_mlp<<<130 * 5, 256, 0, stream>>>(X, ueW1, ueb1, ueW2, ueb2,
                                     urW1, urb1, urW2, urb2,
                                     ieW1, ieb1, ieW2, ieb2,
                                     irW1, irb1, irW2, irb2,
                                     e1, e2, r1, r2, r3);
  k_gram<<<64 * 9, 256, 0, stream>>>(e1, e2, r1, r2, r3, Wcoef);
  k_scan<<<B_ * 8, 64, 0, stream>>>(e1, e2, Wcoef, acd);
  k_infer<<<B_, 256, 0, stream>>>(acd, e1, e2, r1, r2, r3, qe1, qr1, qr2, qr3,
                                  lng, lnb, isum);
  k_final<<<V_ / 64, 256, 0, stream>>>(isum, Zm, outF);
}

// Round 6
// 305.790 us; speedup vs baseline: 1.7274x; 1.0801x over previous
//
#include <hip/hip_runtime.h>
#include <math.h>

// Problem constants
#define B_   64
#define S_   64
#define W_   12
#define V_   32000
#define SYM_ 128
#define HID_ 256
#define E_   64
#define R_   32

// ---------------------------------------------------------------------------
// K1: embedding sums for story (rows 0..4095) and query (rows 4096..4159)
// ---------------------------------------------------------------------------
__global__ __launch_bounds__(128) void k_embed(
    const int* __restrict__ story, const int* __restrict__ query,
    const float* __restrict__ we, const float* __restrict__ pe,
    float* __restrict__ X) {
  int row = blockIdx.x;
  int e = threadIdx.x;
  const int* idx = (row < 4096) ? story + row * W_ : query + (row - 4096) * W_;
  float acc = 0.f;
#pragma unroll
  for (int w = 0; w < W_; ++w)
    acc = fmaf(we[(long)idx[w] * SYM_ + e], pe[w * SYM_ + e], acc);
  X[row * SYM_ + e] = acc;
}

// ---------------------------------------------------------------------------
// K2: two-layer MLP heads over 4160 rows (unchanged from R5)
// ---------------------------------------------------------------------------
__global__ __launch_bounds__(256) void k_mlp(
    const float* __restrict__ X,
    const float* __restrict__ ueW1, const float* __restrict__ ueb1,
    const float* __restrict__ ueW2, const float* __restrict__ ueb2,
    const float* __restrict__ urW1, const float* __restrict__ urb1,
    const float* __restrict__ urW2, const float* __restrict__ urb2,
    const float* __restrict__ ieW1, const float* __restrict__ ieb1,
    const float* __restrict__ ieW2, const float* __restrict__ ieb2,
    const float* __restrict__ irW1, const float* __restrict__ irb1,
    const float* __restrict__ irW2, const float* __restrict__ irb2,
    float* __restrict__ oE0, float* __restrict__ oE1,
    float* __restrict__ oR0, float* __restrict__ oR1, float* __restrict__ oR2) {
  __shared__ float XT[128 * 33];
  __shared__ float HT[64 * 33];

  int h = blockIdx.x % 5;
  int tile = blockIdx.x / 5;
  int rowbase = tile * 32;
  bool isQ = (rowbase >= 4096);
  bool isE = (h < 2);
  const float* eW1 = isQ ? ieW1 : ueW1;
  const float* eb1 = isQ ? ieb1 : ueb1;
  const float* eW2 = isQ ? ieW2 : ueW2;
  const float* eb2 = isQ ? ieb2 : ueb2;
  const float* rW1 = isQ ? irW1 : urW1;
  const float* rb1 = isQ ? irb1 : urb1;
  const float* rW2 = isQ ? irW2 : urW2;
  const float* rb2 = isQ ? irb2 : urb2;
  const float* W1 = isE ? eW1 + h * (SYM_ * HID_) : rW1 + (h - 2) * (SYM_ * HID_);
  const float* b1 = isE ? eb1 + h * HID_ : rb1 + (h - 2) * HID_;
  const float* W2 = isE ? eW2 + h * (HID_ * E_) : rW2 + (h - 2) * (HID_ * R_);
  const float* b2 = isE ? eb2 + h * E_ : rb2 + (h - 2) * R_;
  float* out = (h == 0) ? oE0 : (h == 1) ? oE1 : (h == 2) ? oR0 : (h == 3) ? oR1 : oR2;

  int tid = threadIdx.x;
  for (int i = tid; i < 32 * 128; i += 256) {
    int row = i >> 7, k = i & 127;
    XT[k * 33 + row] = X[(long)(rowbase + row) * SYM_ + k];
  }
  __syncthreads();

  int tr = tid >> 4, tc = tid & 15;
  float accE0[4] = {}, accE1[4] = {};
  float accR0[2] = {}, accR1[2] = {};

  for (int p = 0; p < 4; ++p) {
    int cbase = p * 64;
    float4 b1v = *(const float4*)(b1 + cbase + 4 * tc);
    float a0[4] = {}, a1[4] = {};
#pragma unroll 8
    for (int k = 0; k < 128; ++k) {
      float x0 = XT[k * 33 + 2 * tr];
      float x1 = XT[k * 33 + 2 * tr + 1];
      float4 wb = *(const float4*)(W1 + k * HID_ + cbase + 4 * tc);
      a0[0] = fmaf(x0, wb.x, a0[0]); a0[1] = fmaf(x0, wb.y, a0[1]);
      a0[2] = fmaf(x0, wb.z, a0[2]); a0[3] = fmaf(x0, wb.w, a0[3]);
      a1[0] = fmaf(x1, wb.x, a1[0]); a1[1] = fmaf(x1, wb.y, a1[1]);
      a1[2] = fmaf(x1, wb.z, a1[2]); a1[3] = fmaf(x1, wb.w, a1[3]);
    }
    __syncthreads();
    float b1s[4] = {b1v.x, b1v.y, b1v.z, b1v.w};
#pragma unroll
    for (int j = 0; j < 4; ++j) {
      HT[(4 * tc + j) * 33 + 2 * tr] = tanhf(a0[j] + b1s[j]);
      HT[(4 * tc + j) * 33 + 2 * tr + 1] = tanhf(a1[j] + b1s[j]);
    }
    __syncthreads();
    if (isE) {
#pragma unroll 4
      for (int c = 0; c < 64; ++c) {
        float h0 = HT[c * 33 + 2 * tr];
        float h1 = HT[c * 33 + 2 * tr + 1];
        float4 w4 = *(const float4*)(W2 + (long)(cbase + c) * E_ + 4 * tc);
        accE0[0] = fmaf(h0, w4.x, accE0[0]); accE0[1] = fmaf(h0, w4.y, accE0[1]);
        accE0[2] = fmaf(h0, w4.z, accE0[2]); accE0[3] = fmaf(h0, w4.w, accE0[3]);
        accE1[0] = fmaf(h1, w4.x, accE1[0]); accE1[1] = fmaf(h1, w4.y, accE1[1]);
        accE1[2] = fmaf(h1, w4.z, accE1[2]); accE1[3] = fmaf(h1, w4.w, accE1[3]);
      }
    } else {
#pragma unroll 4
      for (int c = 0; c < 64; ++c) {
        float h0 = HT[c * 33 + 2 * tr];
        float h1 = HT[c * 33 + 2 * tr + 1];
        float2 w2 = *(const float2*)(W2 + (long)(cbase + c) * R_ + 2 * tc);
        accR0[0] = fmaf(h0, w2.x, accR0[0]); accR0[1] = fmaf(h0, w2.y, accR0[1]);
        accR1[0] = fmaf(h1, w2.x, accR1[0]); accR1[1] = fmaf(h1, w2.y, accR1[1]);
      }
    }
  }
  int r0 = rowbase + 2 * tr;
  if (isE) {
    float4 b2v = *(const float4*)(b2 + 4 * tc);
    *(float4*)(out + (long)r0 * E_ + 4 * tc) =
        make_float4(accE0[0] + b2v.x, accE0[1] + b2v.y, accE0[2] + b2v.z, accE0[3] + b2v.w);
    *(float4*)(out + (long)(r0 + 1) * E_ + 4 * tc) =
        make_float4(accE1[0] + b2v.x, accE1[1] + b2v.y, accE1[2] + b2v.z, accE1[3] + b2v.w);
  } else {
    float2 b2v = *(const float2*)(b2 + 2 * tc);
    *(float2*)(out + (long)r0 * R_ + 2 * tc) =
        make_float2(accR0[0] + b2v.x, accR0[1] + b2v.y);
    *(float2*)(out + (long)(r0 + 1) * R_ + 2 * tc) =
        make_float2(accR1[0] + b2v.x, accR1[1] + b2v.y);
  }
}

// ---------------------------------------------------------------------------
// K_gram: W[b,m,s,j] = (sE_s . jE_j) * (sR_s . jR_j)   (unchanged)
// ---------------------------------------------------------------------------
__global__ __launch_bounds__(256) void k_gram(
    const float* __restrict__ e1, const float* __restrict__ e2,
    const float* __restrict__ r1, const float* __restrict__ r2,
    const float* __restrict__ r3, float* __restrict__ Wc) {
  int b = blockIdx.x / 9, m = blockIdx.x % 9;
  const float* sE = ((m < 6) ? e1 : e2) + (long)b * S_ * E_;
  const float* jE = ((m == 2 || m == 5 || m == 8) ? e2 : e1) + (long)b * S_ * E_;
  int sk = m / 3, jk = m % 3;
  const float* sR = ((sk == 0) ? r1 : (sk == 1) ? r2 : r3) + (long)b * S_ * R_;
  const float* jR = ((jk == 0) ? r1 : (jk == 1) ? r2 : r3) + (long)b * S_ * R_;

  __shared__ float Es[64][68], Ej[64][68], Rs[64][36], Rj[64][36];
  int tid = threadIdx.x;
  for (int i = tid; i < 1024; i += 256) {
    int row = i >> 4, c = i & 15;
    *(float4*)&Es[row][4 * c] = *(const float4*)(sE + row * 64 + 4 * c);
    *(float4*)&Ej[row][4 * c] = *(const float4*)(jE + row * 64 + 4 * c);
  }
  for (int i = tid; i < 512; i += 256) {
    int row = i >> 3, c = i & 7;
    *(float4*)&Rs[row][4 * c] = *(const float4*)(sR + row * 32 + 4 * c);
    *(float4*)&Rj[row][4 * c] = *(const float4*)(jR + row * 32 + 4 * c);
  }
  __syncthreads();

  int s0 = (tid >> 4) * 4, j0 = (tid & 15) * 4;
  float ed[4][4] = {}, rd[4][4] = {};
#pragma unroll 4
  for (int k = 0; k < 16; ++k) {
    float4 es[4], ej[4];
#pragma unroll
    for (int i = 0; i < 4; ++i) {
      es[i] = *(const float4*)&Es[s0 + i][4 * k];
      ej[i] = *(const float4*)&Ej[j0 + i][4 * k];
    }
#pragma unroll
    for (int i = 0; i < 4; ++i)
#pragma unroll
      for (int j = 0; j < 4; ++j)
        ed[i][j] = fmaf(es[i].x, ej[j].x, fmaf(es[i].y, ej[j].y,
                   fmaf(es[i].z, ej[j].z, fmaf(es[i].w, ej[j].w, ed[i][j]))));
  }
#pragma unroll 4
  for (int k = 0; k < 8; ++k) {
    float4 rs[4], rj[4];
#pragma unroll
    for (int i = 0; i < 4; ++i) {
      rs[i] = *(const float4*)&Rs[s0 + i][4 * k];
      rj[i] = *(const float4*)&Rj[j0 + i][4 * k];
    }
#pragma unroll
    for (int i = 0; i < 4; ++i)
#pragma unroll
      for (int j = 0; j < 4; ++j)
        rd[i][j] = fmaf(rs[i].x, rj[j].x, fmaf(rs[i].y, rj[j].y,
                   fmaf(rs[i].z, rj[j].z, fmaf(rs[i].w, rj[j].w, rd[i][j]))));
  }
  float* wout = Wc + (((long)(b * 9 + m) * 64) * 64);
#pragma unroll
  for (int i = 0; i < 4; ++i) {
    float4 o4 = make_float4(ed[i][0] * rd[i][0], ed[i][1] * rd[i][1],
                            ed[i][2] * rd[i][2], ed[i][3] * rd[i][3]);
    *(float4*)(wout + (s0 + i) * 64 + j0) = o4;
  }
}

// ---------------------------------------------------------------------------
// K_scan v5 (outer-product form, no reductions):
// lane = s. When h_j is broadcast (v_readlane, VALU-speed), every lane
// accumulates its rank-1 term: pW[s] += Wa[s,j]a_j + Wc[s,j]c_j + Wd[s,j]d_j
// (same pM, pB). Lane j+1 then holds COMPLETE hats -> next candidate h is
// formed on all lanes, latched by its owner via ?:. No LDS, no barriers,
// no shuffles. Each wave handles 2 f's (W rows reused). Grid = g*64+b so all
// 8 blocks of a batch share an XCD's L2 copy of W.
// ---------------------------------------------------------------------------
#define WCOMP(v, jj) ((jj) == 0 ? (v).x : (jj) == 1 ? (v).y : (jj) == 2 ? (v).z : (v).w)

__global__ __launch_bounds__(256) void k_scan(
    const float* __restrict__ e1g, const float* __restrict__ e2g,
    const float* __restrict__ Wc, float4* __restrict__ acd) {
  int blk = blockIdx.x;
  int b = blk & 63;
  int g = blk >> 6;                // 0..7
  int wv = threadIdx.x >> 6;       // 0..3
  int lane = threadIdx.x & 63;     // = s
  int f0 = g * 8 + wv * 2;
  int f1 = f0 + 1;
  const float* Wb = Wc + (long)b * 9 * 4096 + lane * 64;
  long eoff = ((long)b * 64 + lane) * 64;
  float e1x = e1g[eoff + f0], e1y = e1g[eoff + f1];
  float e2x = e2g[eoff + f0], e2y = e2g[eoff + f1];

  float pW0 = 0.f, pM0 = 0.f, pB0 = 0.f;
  float pW1 = 0.f, pM1 = 0.f, pB1 = 0.f;
  float ca0 = e2x, cc0 = 0.f, cd0 = e1x;
  float ca1 = e2y, cc1 = 0.f, cd1 = e1y;
  float ka0 = 0.f, kc0 = 0.f, kd0 = 0.f;
  float ka1 = 0.f, kc1 = 0.f, kd1 = 0.f;

  for (int j0 = 0; j0 < 64; j0 += 4) {
    float4 w[9];
#pragma unroll
    for (int m = 0; m < 9; ++m)
      w[m] = *(const float4*)(Wb + m * 4096 + j0);
#pragma unroll
    for (int jj = 0; jj < 4; ++jj) {
      int j = j0 + jj;
      // broadcast h_j from lane j (uniform index -> v_readlane, VALU pipe)
      float aj0 = __int_as_float(__builtin_amdgcn_readlane(__float_as_int(ca0), j));
      float cj0 = __int_as_float(__builtin_amdgcn_readlane(__float_as_int(cc0), j));
      float dj0 = __int_as_float(__builtin_amdgcn_readlane(__float_as_int(cd0), j));
      float aj1 = __int_as_float(__builtin_amdgcn_readlane(__float_as_int(ca1), j));
      float cj1 = __int_as_float(__builtin_amdgcn_readlane(__float_as_int(cc1), j));
      float dj1 = __int_as_float(__builtin_amdgcn_readlane(__float_as_int(cd1), j));
      // latch owner's final h_s
      bool own = (lane == j);
      ka0 = own ? ca0 : ka0; kc0 = own ? cc0 : kc0; kd0 = own ? cd0 : kd0;
      ka1 = own ? ca1 : ka1; kc1 = own ? cc1 : kc1; kd1 = own ? cd1 : kd1;
      // rank-1 accumulate
      float wa = WCOMP(w[0], jj), wc = WCOMP(w[1], jj), wd = WCOMP(w[2], jj);
      float ma = WCOMP(w[3], jj), mc = WCOMP(w[4], jj), md = WCOMP(w[5], jj);
      float ba = WCOMP(w[6], jj), bc = WCOMP(w[7], jj), bd = WCOMP(w[8], jj);
      pW0 = fmaf(wa, aj0, pW0); pW0 = fmaf(wc, cj0, pW0); pW0 = fmaf(wd, dj0, pW0);
      pM0 = fmaf(ma, aj0, pM0); pM0 = fmaf(mc, cj0, pM0); pM0 = fmaf(md, dj0, pM0);
      pB0 = fmaf(ba, aj0, pB0); pB0 = fmaf(bc, cj0, pB0); pB0 = fmaf(bd, dj0, pB0);
      pW1 = fmaf(wa, aj1, pW1); pW1 = fmaf(wc, cj1, pW1); pW1 = fmaf(wd, dj1, pW1);
      pM1 = fmaf(ma, aj1, pM1); pM1 = fmaf(mc, cj1, pM1); pM1 = fmaf(md, dj1, pM1);
      pB1 = fmaf(ba, aj1, pB1); pB1 = fmaf(bc, cj1, pB1); pB1 = fmaf(bd, dj1, pB1);
      // new candidates (valid for lane j+1 at next step)
      ca0 = e2x - pW0; cc0 = pW0 - pM0; cd0 = e1x - pB0;
      ca1 = e2y - pW1; cc1 = pW1 - pM1; cd1 = e1y - pB1;
    }
  }
  acd[eoff + f0] = make_float4(ka0, kc0, kd0, 0.f);
  acd[eoff + f1] = make_float4(ka1, kc1, kd1, 0.f);
}

// ---------------------------------------------------------------------------
// K_infer (unchanged from R5)
// ---------------------------------------------------------------------------
__global__ __launch_bounds__(256) void k_infer(
    const float4* __restrict__ acd,
    const float* __restrict__ e1, const float* __restrict__ e2,
    const float* __restrict__ r1, const float* __restrict__ r2,
    const float* __restrict__ r3,
    const float* __restrict__ qe1, const float* __restrict__ qr1,
    const float* __restrict__ qr2, const float* __restrict__ qr3,
    const float* __restrict__ lng, const float* __restrict__ lnb,
    float* __restrict__ isum) {
  int b = blockIdx.x, tid = threadIdx.x;
  __shared__ float vlds[9 * 64];
  __shared__ float ivec[64];
  __shared__ float u1s[64], u2s[64];
  __shared__ float dsc[64];
  const float4* ab = acd + (long)b * 4096;

  for (int idx = tid; idx < 576; idx += 256) {
    int pk = idx >> 6, j = idx & 63;
    int p = pk / 3, k = pk % 3;
    const float* rv = ((k == 0) ? r1 : (k == 1) ? r2 : r3) + ((long)b * 64 + j) * 32;
    const float* q = ((p == 0) ? qr1 : (p == 1) ? qr2 : qr3) + b * 32;
    float acc = 0.f;
#pragma unroll
    for (int t = 0; t < 8; ++t) {
      float4 rv4 = *(const float4*)(rv + 4 * t);
      float4 q4 = *(const float4*)(q + 4 * t);
      acc = fmaf(rv4.x, q4.x, fmaf(rv4.y, q4.y,
            fmaf(rv4.z, q4.z, fmaf(rv4.w, q4.w, acc))));
    }
    vlds[pk * 64 + j] = acc;
  }
  if (tid < 64) ivec[tid] = qe1[b * 64 + tid];
  __syncthreads();

  int lane = tid & 63, wv = tid >> 6;
  int fx = wv * 16 + (lane & 15);
  int q = lane >> 4;
  float isacc = 0.f;
  for (int p = 0; p < 3; ++p) {
    if (tid < 128) {
      int which = tid >> 6, j = tid & 63;
      const float* erow = (which ? e2 : e1) + ((long)b * 64 + j) * 64;
      const float4* iv4 = (const float4*)ivec;
      float acc = 0.f;
#pragma unroll
      for (int t = 0; t < 16; ++t) {
        float4 ev = *(const float4*)(erow + 4 * t);
        float4 c4 = iv4[t];
        acc = fmaf(ev.x, c4.x, fmaf(ev.y, c4.y,
              fmaf(ev.z, c4.z, fmaf(ev.w, c4.w, acc))));
      }
      if (which) u2s[j] = acc; else u1s[j] = acc;
    }
    __syncthreads();
    float part = 0.f;
#pragma unroll 4
    for (int jj = 0; jj < 16; ++jj) {
      int j = q * 16 + jj;
      float4 h = ab[j * 64 + fx];
      float ca = u1s[j] * vlds[(p * 3 + 0) * 64 + j];
      float cc = u1s[j] * vlds[(p * 3 + 1) * 64 + j];
      float cd = u2s[j] * vlds[(p * 3 + 2) * 64 + j];
      part = fmaf(ca, h.x, fmaf(cc, h.y, fmaf(cd, h.z, part)));
    }
    part += __shfl_xor(part, 16, 64);
    part += __shfl_xor(part, 32, 64);
    if (q == 0) dsc[fx] = part;
    __syncthreads();
    if (tid < 64) {
      float v = dsc[tid];
      float mu = v;
#pragma unroll
      for (int mm = 1; mm <= 32; mm <<= 1) mu += __shfl_xor(mu, mm, 64);
      mu *= (1.f / 64.f);
      float d = v - mu;
      float vr = d * d;
#pragma unroll
      for (int mm = 1; mm <= 32; mm <<= 1) vr += __shfl_xor(vr, mm, 64);
      vr *= (1.f / 64.f);
      float iv = d * (1.f / sqrtf(vr + 1e-5f)) * lng[p * 64 + tid] + lnb[p * 64 + tid];
      ivec[tid] = iv;
      isacc += iv;
    }
    __syncthreads();
  }
  if (tid < 64) isum[b * 64 + tid] = isacc;
}

// ---------------------------------------------------------------------------
// K5: out[b,v] = sum_e isum[b,e] * Z[e,v]   (unchanged)
// ---------------------------------------------------------------------------
__global__ __launch_bounds__(256) void k_final(
    const float* __restrict__ isum, const float* __restrict__ Zm,
    float* __restrict__ out) {
  __shared__ float isT[64 * 68];
  int tid = threadIdx.x;
  for (int i = tid; i < 4096; i += 256) {
    int bb = i >> 6, e = i & 63;
    isT[e * 68 + bb] = isum[i];
  }
  __syncthreads();
  int tr = tid >> 4, tc = tid & 15;
  int v0 = blockIdx.x * 64 + tc * 4;
  float acc[4][4] = {};
#pragma unroll 2
  for (int e = 0; e < 64; ++e) {
    float4 a4 = *(const float4*)&isT[e * 68 + 4 * tr];
    float4 z4 = *(const float4*)(Zm + (long)e * V_ + v0);
    float as[4] = {a4.x, a4.y, a4.z, a4.w};
    float zs[4] = {z4.x, z4.y, z4.z, z4.w};
#pragma unroll
    for (int i = 0; i < 4; ++i)
#pragma unroll
      for (int j = 0; j < 4; ++j) acc[i][j] = fmaf(as[i], zs[j], acc[i][j]);
  }
#pragma unroll
  for (int i = 0; i < 4; ++i) {
    float4 o4 = make_float4(acc[i][0], acc[i][1], acc[i][2], acc[i][3]);
    *(float4*)(out + (long)(4 * tr + i) * V_ + v0) = o4;
  }
}

// ---------------------------------------------------------------------------
extern "C" void kernel_launch(void* const* d_in, const int* in_sizes, int n_in,
                              void* d_out, int out_size, void* d_ws, size_t ws_size,
                              hipStream_t stream) {
  const int* story = (const int*)d_in[0];
  const int* query = (const int*)d_in[1];
  const float* we = (const float*)d_in[2];
  const float* pe = (const float*)d_in[3];
  const float* ueW1 = (const float*)d_in[4];
  const float* ueb1 = (const float*)d_in[5];
  const float* ueW2 = (const float*)d_in[6];
  const float* ueb2 = (const float*)d_in[7];
  const float* urW1 = (const float*)d_in[8];
  const float* urb1 = (const float*)d_in[9];
  const float* urW2 = (const float*)d_in[10];
  const float* urb2 = (const float*)d_in[11];
  const float* ieW1 = (const float*)d_in[12];
  const float* ieb1 = (const float*)d_in[13];
  const float* ieW2 = (const float*)d_in[14];
  const float* ieb2 = (const float*)d_in[15];
  const float* irW1 = (const float*)d_in[16];
  const float* irb1 = (const float*)d_in[17];
  const float* irW2 = (const float*)d_in[18];
  const float* irb2 = (const float*)d_in[19];
  const float* lng = (const float*)d_in[20];
  const float* lnb = (const float*)d_in[21];
  const float* Zm = (const float*)d_in[22];

  float* ws = (float*)d_ws;
  float* X = ws;                        // 4160*128 = 532480
  float* e1 = X + 532480;               // 4160*64  = 266240
  float* e2 = e1 + 266240;              // 266240
  float* r1 = e2 + 266240;              // 4160*32  = 133120
  float* r2 = r1 + 133120;              // 133120
  float* r3 = r2 + 133120;              // 133120
  float* isum = r3 + 133120;            // 4096
  float* Wcoef = isum + 4096;           // 9*64*4096 = 2359296
  float4* acd = (float4*)(Wcoef + 2359296);  // 64*64*64 float4 = 4 MB
  float* qe1 = e1 + 4096 * 64;
  float* qr1 = r1 + 4096 * 32;
  float* qr2 = r2 + 4096 * 32;
  float* qr3 = r3 + 4096 * 32;
  float* outF = (float*)d_out;

  k_embed<<<4160, 128, 0, stream>>>(story, query, we, pe, X);
  k_mlp<<<130 * 5, 256, 0, stream>>>(X, ueW1, ueb1, ueW2, ueb2,
                                     urW1, urb1, urW2, urb2,
                                     ieW1, ieb1, ieW2, ieb2,
                                     irW1, irb1, irW2, irb2,
                                     e1, e2, r1, r2, r3);
  k_gram<<<64 * 9, 256, 0, stream>>>(e1, e2, r1, r2, r3, Wcoef);
  k_scan<<<512, 256, 0, stream>>>(e1, e2, Wcoef, acd);
  k_infer<<<B_, 256, 0, stream>>>(acd, e1, e2, r1, r2, r3, qe1, qr1, qr2, qr3,
                                  lng, lnb, isum);
  k_final<<<V_ / 64, 256, 0, stream>>>(isum, Zm, outF);
}